// Round 4
// baseline (2871.678 us; speedup 1.0000x reference)
//
#include <hip/hip_runtime.h>
#include <cstdint>
#include <cstddef>

// ---------------------------------------------------------------------------
// EnDeModel: GRU encoder (365 steps) -> GRU decoder (90 steps) -> SIRD rollout
// Persistent-grid: 256 WGs x 512 threads (8 waves). Wave w of WG g owns hidden
// unit j = g*8+w: all 3 (enc) / 6 (dec) gate rows for j live in that wave's
// registers, so gate math completes in-wave (no cross-wave reduction tail).
//
// Cross-WG handoff: each h element is a 64-bit word {tag=step<<32 | fp32 bits}.
// Writer: single 8B agent-scope atomic store per wave (data IS the signal; no
// flags, no fences). Reader: 16B cache-bypassing wide loads
// (global_load_dwordx4 sc0 sc1) covering 2 tagged u64s each -- coalescable,
// 8x fewer MALL requests than per-lane atomic polls (round-3 limiter: the
// MALL is request-rate bound, 0.5M discrete atomic requests per poll round).
// Each 16B load is serviced from one 64B sector in a single fill -> the
// aligned 8B halves don't tear vs the 8B atomic stores.
// Depth-2 ring is safe: a tag t+2 write requires all tag t+1 writes, which
// require every WG to have read tag t.
//
// Betas: decoder hp rows dumped to hstore[90][2048] (plain stores, off the
// critical path); final kernel does the 90 Wa-dots + 119-step SIRD chain.
// ---------------------------------------------------------------------------

#define HID   2048
#define T_ENC 365
#define F_DEC 90
#define NWG   256
#define NTH   512

// ws layout (4-byte units)
#define WS_P      0                 // p[6144]
#define WS_Q      6144              // q[6144]
#define WS_HBUF   12288             // u64 hbuf[2][2048]  (tagged h ring)
#define WS_DX0    20480             // u64 dx0[2048]      (tagged raw y)
#define WS_HSTORE 24576             // float hstore[90][2048]

typedef unsigned long long u64;

__device__ __forceinline__ float sigm(float x) {
    return 1.0f / (1.0f + __expf(-x));
}
__device__ __forceinline__ float tanh_f(float x) {
    return 1.0f - 2.0f / (1.0f + __expf(2.0f * x));
}
__device__ __forceinline__ unsigned bf16rne(float f) {
    unsigned x = __float_as_uint(f);
    return (x + 0x7fffu + ((x >> 16) & 1u)) >> 16;
}
__device__ __forceinline__ unsigned packbf(float lo, float hi) {
    return bf16rne(lo) | (bf16rne(hi) << 16);
}

__device__ __forceinline__ void tst(u64* p, u64 v) {
    __hip_atomic_store(p, v, __ATOMIC_RELAXED, __HIP_MEMORY_SCOPE_AGENT);
}
__device__ __forceinline__ u64 mk(unsigned tag, float v) {
    return ((u64)tag << 32) | (u64)__float_as_uint(v);
}

// Thread tid covers u64 elements {2t, 2t+1} and {1024+2t, 1024+2t+1} via two
// 16B bypass loads (uint4: x=payload0, y=tag0, z=payload1, w=tag1).
// Wave exits when all its 256 elements carry `tag`; payloads land in lds[].
__device__ __forceinline__ void poll_to_lds(const u64* __restrict__ buf,
                                            unsigned tag, int tid,
                                            float* __restrict__ lds) {
    const u64* p0 = buf + 2 * tid;
    const u64* p1 = buf + 1024 + 2 * tid;
    uint4 a, b;
    while (true) {
        asm volatile(
            "global_load_dwordx4 %0, %2, off sc0 sc1\n\t"
            "global_load_dwordx4 %1, %3, off sc0 sc1\n\t"
            "s_waitcnt vmcnt(0)"
            : "=&v"(a), "=&v"(b)
            : "v"(p0), "v"(p1)
            : "memory");
        bool ok = (a.y == tag) & (a.w == tag) & (b.y == tag) & (b.w == tag);
        if (__ballot(ok) == ~0ull) break;
    }
    *(float2*)(lds + 2 * tid) =
        make_float2(__uint_as_float(a.x), __uint_as_float(a.z));
    *(float2*)(lds + 1024 + 2 * tid) =
        make_float2(__uint_as_float(b.x), __uint_as_float(b.z));
}

// p[r] = enc_Wih[r,:] @ Wb ; q[r] = enc_Wih[r,:] @ bb + enc_bih[r]
__global__ void prep_pq(const float* __restrict__ Wih, const float* __restrict__ Wb,
                        const float* __restrict__ bb, const float* __restrict__ bih,
                        float* __restrict__ p, float* __restrict__ q) {
    int wave = threadIdx.x >> 6, lane = threadIdx.x & 63;
    int row = blockIdx.x * 4 + wave;
    const float* wr = Wih + (size_t)row * HID;
    float ap = 0.f, aq = 0.f;
    for (int k = lane; k < HID; k += 64) {
        float w = wr[k];
        ap += w * Wb[k];
        aq += w * bb[k];
    }
#pragma unroll
    for (int m = 1; m < 64; m <<= 1) {
        ap += __shfl_xor(ap, m);
        aq += __shfl_xor(aq, m);
    }
    if (lane == 0) {
        p[row] = ap;
        q[row] = aq + bih[row];
    }
}

__global__ __launch_bounds__(NTH, 1) void persist(
    const float* __restrict__ hu, const float* __restrict__ encWhh,
    const float* __restrict__ encBhh, const float* __restrict__ decWih,
    const float* __restrict__ decWhh, const float* __restrict__ decBih,
    const float* __restrict__ decBhh, const float* __restrict__ p,
    const float* __restrict__ q, u64* hbuf, u64* dx0, float* hstore) {
    const int wg = blockIdx.x, tid = threadIdx.x;
    const int wave = tid >> 6, lane = tid & 63;
    const int j = wg * 8 + wave;

    __shared__ float h_lds[HID], x_lds[HID];
    __shared__ float p_l[24], q_l[24], ebhh[24], dbih[24], dbhh[24];
    __shared__ float u_l[T_ENC];

    // --- LDS preloads (once) ---
    for (int idx = tid; idx < T_ENC; idx += NTH) u_l[idx] = hu[idx];
    if (tid < 24) {
        int g = tid >> 3, jj = tid & 7;
        int r = g * HID + wg * 8 + jj;
        p_l[tid] = p[r];
        q_l[tid] = q[r];
        ebhh[tid] = encBhh[r];
        dbih[tid] = decBih[r];
        dbhh[tid] = decBhh[r];
    }

    // --- encoder Whh rows for unit j -> fp32 registers (3 rows/wave) ---
    // lane covers k in {4*lane + 256*i + e | i=0..7, e=0..3}
    float4 We[3][8];
#pragma unroll
    for (int g = 0; g < 3; g++) {
        const float* base = encWhh + (size_t)(g * HID + j) * HID;
#pragma unroll
        for (int i = 0; i < 8; i++)
            We[g][i] = *reinterpret_cast<const float4*>(base + 4 * lane + 256 * i);
    }

    // =========================== encoder: 365 steps =========================
    for (int t = 0; t < T_ENC; t++) {
        if (t == 0) {
            for (int idx = tid; idx < HID; idx += NTH) h_lds[idx] = 0.f;
        } else {
            poll_to_lds(hbuf + (t & 1) * HID, (unsigned)t, tid, h_lds);
        }
        __syncthreads();

        float4 hreg[8];
#pragma unroll
        for (int i = 0; i < 8; i++)
            hreg[i] = *reinterpret_cast<const float4*>(&h_lds[4 * lane + 256 * i]);

        float v0, v1, v2;
        {
            float a0 = 0.f, a1 = 0.f, a2 = 0.f, a3 = 0.f;
            float b0 = 0.f, b1 = 0.f, b2 = 0.f, b3 = 0.f;
            float c0 = 0.f, c1 = 0.f, c2 = 0.f, c3 = 0.f;
#pragma unroll
            for (int i = 0; i < 8; i++) {
                float4 h4 = hreg[i];
                float4 wr_ = We[0][i], wz_ = We[1][i], wc_ = We[2][i];
                a0 += wr_.x * h4.x; a1 += wr_.y * h4.y;
                a2 += wr_.z * h4.z; a3 += wr_.w * h4.w;
                b0 += wz_.x * h4.x; b1 += wz_.y * h4.y;
                b2 += wz_.z * h4.z; b3 += wz_.w * h4.w;
                c0 += wc_.x * h4.x; c1 += wc_.y * h4.y;
                c2 += wc_.z * h4.z; c3 += wc_.w * h4.w;
            }
            v0 = (a0 + a1) + (a2 + a3);
            v1 = (b0 + b1) + (b2 + b3);
            v2 = (c0 + c1) + (c2 + c3);
        }
#pragma unroll
        for (int m = 1; m < 64; m <<= 1) {
            v0 += __shfl_xor(v0, m);
            v1 += __shfl_xor(v1, m);
            v2 += __shfl_xor(v2, m);
        }

        if (lane == 0) {
            float u = u_l[t];
            float gir = u * p_l[wave] + q_l[wave];
            float giz = u * p_l[8 + wave] + q_l[8 + wave];
            float gic = u * p_l[16 + wave] + q_l[16 + wave];
            float r = sigm(gir + v0 + ebhh[wave]);
            float z = sigm(giz + v1 + ebhh[8 + wave]);
            float c = tanh_f(gic + r * (v2 + ebhh[16 + wave]));
            float hp = (1.f - z) * c + z * h_lds[j];
            float hs = sigm(hp);
            tst(hbuf + ((t + 1) & 1) * HID + j, mk((unsigned)(t + 1), hs));
            if (t == T_ENC - 1) tst(dx0 + j, mk((unsigned)T_ENC, hp));
        }
    }

    // --- decoder Wih+Whh rows for unit j -> packed bf16 (6 rows/wave) ---
    unsigned Wd[6][8][2];
#pragma unroll
    for (int g = 0; g < 6; g++) {
        const float* src = (g < 3)
            ? decWih + (size_t)(g * HID + j) * HID
            : decWhh + (size_t)((g - 3) * HID + j) * HID;
#pragma unroll
        for (int i = 0; i < 8; i++) {
            float4 w = *reinterpret_cast<const float4*>(src + 4 * lane + 256 * i);
            Wd[g][i][0] = packbf(w.x, w.y);
            Wd[g][i][1] = packbf(w.z, w.w);
        }
    }

    // =========================== decoder: 90 steps ==========================
    for (int s = 0; s < F_DEC; s++) {
        unsigned rt = (unsigned)(T_ENC + s);
        poll_to_lds(hbuf + (rt & 1) * HID, rt, tid, h_lds);
        if (s == 0) poll_to_lds(dx0, (unsigned)T_ENC, tid, x_lds);
        __syncthreads();

        const float* xs = (s == 0) ? x_lds : h_lds;
        float4 vx[8], vh[8];
#pragma unroll
        for (int i = 0; i < 8; i++) {
            vx[i] = *reinterpret_cast<const float4*>(&xs[4 * lane + 256 * i]);
            vh[i] = *reinterpret_cast<const float4*>(&h_lds[4 * lane + 256 * i]);
        }

        float d[6];
#pragma unroll
        for (int g = 0; g < 6; g++) {
            float a0 = 0.f, a1 = 0.f, a2 = 0.f, a3 = 0.f;
#pragma unroll
            for (int i = 0; i < 8; i++) {
                unsigned u0 = Wd[g][i][0], u1 = Wd[g][i][1];
                float4 v4 = (g < 3) ? vx[i] : vh[i];
                a0 += __uint_as_float(u0 << 16) * v4.x;
                a1 += __uint_as_float(u0 & 0xffff0000u) * v4.y;
                a2 += __uint_as_float(u1 << 16) * v4.z;
                a3 += __uint_as_float(u1 & 0xffff0000u) * v4.w;
            }
            d[g] = (a0 + a1) + (a2 + a3);
        }
#pragma unroll
        for (int m = 1; m < 64; m <<= 1) {
#pragma unroll
            for (int g = 0; g < 6; g++) d[g] += __shfl_xor(d[g], m);
        }

        if (lane == 0) {
            float r = sigm(d[0] + dbih[wave] + d[3] + dbhh[wave]);
            float z = sigm(d[1] + dbih[8 + wave] + d[4] + dbhh[8 + wave]);
            float c = tanh_f(d[2] + dbih[16 + wave] +
                             r * (d[5] + dbhh[16 + wave]));
            float hp = (1.f - z) * c + z * h_lds[j];
            tst(hbuf + ((rt + 1) & 1) * HID + j, mk(rt + 1, hp));
            hstore[s * HID + j] = hp;  // off-path, read by sird_k after kernel
        }
    }
}

__global__ void sird_k(const float* __restrict__ sird, const float* __restrict__ Wa,
                       const float* __restrict__ ba, const int* __restrict__ ts_p,
                       const float* __restrict__ hstore, float* __restrict__ out) {
    __shared__ float bpre[96];
    int wave = threadIdx.x >> 6, lane = threadIdx.x & 63;
    const float4* wa4 = (const float4*)Wa;
    for (int s = wave; s < F_DEC; s += 8) {
        const float4* hr = (const float4*)(hstore + (size_t)s * HID);
        float a0 = 0.f, a1 = 0.f, a2 = 0.f, a3 = 0.f;
#pragma unroll
        for (int m = 0; m < 8; m++) {
            float4 w = wa4[lane + 64 * m], h = hr[lane + 64 * m];
            a0 += w.x * h.x;
            a1 += w.y * h.y;
            a2 += w.z * h.z;
            a3 += w.w * h.w;
        }
        float v = (a0 + a1) + (a2 + a3);
#pragma unroll
        for (int m = 1; m < 64; m <<= 1) v += __shfl_xor(v, m);
        if (lane == 0) bpre[s] = v;
    }
    __syncthreads();
    if (threadIdx.x == 0) {
        float s = sird[0], i = sird[1], r = sird[2], d = sird[3], n = sird[4];
        float bl = 0.f;
        for (int t = 0; t < F_DEC; t++) {
            float b = 1.f / (1.f + expf(-(bpre[t] + ba[0])));
            bl = b;
            float si = s * i * b / n, ir = i * 0.05f, id = i * 0.01f;
            s -= si;
            i += si - ir - id;
            r += ir;
            d += id;
        }
        int ts = ts_p[0];
        float* foo = out + 5;
        for (int t = 0; t < ts - 1; t++) {
            float si = s * i * bl / n, ir = i * 0.05f, id = i * 0.01f;
            s -= si;
            i += si - ir - id;
            r += ir;
            d += id;
            foo[t * 5 + 0] = s;
            foo[t * 5 + 1] = i;
            foo[t * 5 + 2] = r;
            foo[t * 5 + 3] = d;
            foo[t * 5 + 4] = n;
        }
        out[0] = s;
        out[1] = i;
        out[2] = r;
        out[3] = d;
        out[4] = n;
    }
}

extern "C" void kernel_launch(void* const* d_in, const int* in_sizes, int n_in,
                              void* d_out, int out_size, void* d_ws, size_t ws_size,
                              hipStream_t stream) {
    const float* hu = (const float*)d_in[0];
    const float* sird = (const float*)d_in[1];
    const int* ts = (const int*)d_in[2];
    const float* Wb = (const float*)d_in[3];
    const float* bb = (const float*)d_in[4];
    const float* eWih = (const float*)d_in[5];
    const float* eWhh = (const float*)d_in[6];
    const float* eBih = (const float*)d_in[7];
    const float* eBhh = (const float*)d_in[8];
    const float* dWih = (const float*)d_in[9];
    const float* dWhh = (const float*)d_in[10];
    const float* dBih = (const float*)d_in[11];
    const float* dBhh = (const float*)d_in[12];
    const float* Wa = (const float*)d_in[13];
    const float* ba = (const float*)d_in[14];

    float* wsf = (float*)d_ws;
    float* p = wsf + WS_P;
    float* q = wsf + WS_Q;
    u64* hbuf = (u64*)(wsf + WS_HBUF);
    u64* dx0 = (u64*)(wsf + WS_DX0);
    float* hstore = wsf + WS_HSTORE;

    // Tags: ws is re-poisoned to 0xAA each launch -> stale tag = 0xAAAAAAAA,
    // never equal to a live tag (1..455), so no flag/buffer init is needed.
    hipLaunchKernelGGL(prep_pq, dim3(6144 / 4), dim3(256), 0, stream, eWih, Wb, bb,
                       eBih, p, q);
    hipLaunchKernelGGL(persist, dim3(NWG), dim3(NTH), 0, stream, hu, eWhh, eBhh,
                       dWih, dWhh, dBih, dBhh, p, q, hbuf, dx0, hstore);
    hipLaunchKernelGGL(sird_k, dim3(1), dim3(NTH), 0, stream, sird, Wa, ba, ts,
                       hstore, (float*)d_out);
}

// Round 5
// 1798.418 us; speedup vs baseline: 1.5968x; 1.5968x over previous
//
#include <hip/hip_runtime.h>
#include <hip/hip_fp16.h>
#include <cstdint>
#include <cstddef>

// ---------------------------------------------------------------------------
// EnDeModel: GRU encoder (365 steps) -> GRU decoder (90 steps) -> SIRD rollout
// Persistent-grid: 256 WGs x 512 threads (8 waves). Wave w of WG g owns hidden
// unit j = g*8+w (3 enc fp32 rows / 6 dec bf16 rows in registers; gates done
// in-wave).
//
// Cross-WG handoff (R5): u64 = {tag32 | fp16 h[2i+1] | fp16 h[2i]} -> 1024
// words for the 2048-vector (halves poll requests vs R3), stored to 8 REPLICA
// buffers; each WG polls only replica (wg&7), so each MALL line is polled by
// 32 WGs instead of 256 (R3/R4 limiter: MALL request pile-up per line).
// Load flavor: 8B agent-scope atomic loads -- measured fastest (R3 5.1us/step
// vs R4 wide sc0sc1 5.9us/step, which also blew FETCH_SIZE up 35%).
// Writer: waves drop h into LDS, one barrier, wave 0 lanes 0-31 store the 4
// packed u64s x 8 replicas. Data IS the signal: no flags, no fences.
// Depth-2 ring safe: tag t+2 write requires all t+1 writes => all read t.
// Tags 1..456 never collide with 0xAA poison.
// ---------------------------------------------------------------------------

#define HID   2048
#define T_ENC 365
#define F_DEC 90
#define NWG   256
#define NTH   512
#define SLOT  8192   // u64s per ring slot (8 replicas x 1024)

// ws layout (4-byte units)
#define WS_P    0        // p[6144]
#define WS_Q    6144     // q[6144]
#define WS_HBUF 12288    // u64 hbuf[2][8][1024]  (tagged fp16-pair ring)
#define WS_DX0  45056    // u64 dx0[8][1024]      (tagged raw y, replicated)
#define WS_HST  61440    // __half hstore[90][2048]

typedef unsigned long long u64;

__device__ __forceinline__ float sigm(float x) {
    return 1.0f / (1.0f + __expf(-x));
}
__device__ __forceinline__ float tanh_f(float x) {
    return 1.0f - 2.0f / (1.0f + __expf(2.0f * x));
}
__device__ __forceinline__ unsigned bf16rne(float f) {
    unsigned x = __float_as_uint(f);
    return (x + 0x7fffu + ((x >> 16) & 1u)) >> 16;
}
__device__ __forceinline__ unsigned packbf(float lo, float hi) {
    return bf16rne(lo) | (bf16rne(hi) << 16);
}

__device__ __forceinline__ u64 tld(const u64* p) {
    return __hip_atomic_load((u64*)p, __ATOMIC_RELAXED, __HIP_MEMORY_SCOPE_AGENT);
}
__device__ __forceinline__ void tst(u64* p, u64 v) {
    __hip_atomic_store(p, v, __ATOMIC_RELAXED, __HIP_MEMORY_SCOPE_AGENT);
}
// {tag | fp16(hi)<<16 | fp16(lo)} ; lo -> element 2i, hi -> element 2i+1
__device__ __forceinline__ u64 mk16(unsigned tag, float lo, float hi) {
    unsigned pk = (unsigned)__half_as_ushort(__float2half(lo)) |
                  ((unsigned)__half_as_ushort(__float2half(hi)) << 16);
    return ((u64)tag << 32) | (u64)pk;
}

// Poll 1024 paired u64s in our replica; unpack payloads into lds[2048].
__device__ __forceinline__ void poll_to_lds(const u64* __restrict__ rep,
                                            unsigned tag, int tid,
                                            float* __restrict__ lds) {
    const u64* p0 = rep + tid;
    const u64* p1 = rep + 512 + tid;
    u64 x0, x1;
    while (true) {
        x0 = tld(p0);
        x1 = tld(p1);
        bool ok = ((unsigned)(x0 >> 32) == tag) & ((unsigned)(x1 >> 32) == tag);
        if (__ballot(ok) == ~0ull) break;
    }
    unsigned lo0 = (unsigned)x0, lo1 = (unsigned)x1;
    float2 f0 = __half22float2(*(__half2*)&lo0);
    float2 f1 = __half22float2(*(__half2*)&lo1);
    *(float2*)(lds + 2 * tid) = f0;
    *(float2*)(lds + 1024 + 2 * tid) = f1;
}

// p[r] = enc_Wih[r,:] @ Wb ; q[r] = enc_Wih[r,:] @ bb + enc_bih[r]
__global__ void prep_pq(const float* __restrict__ Wih, const float* __restrict__ Wb,
                        const float* __restrict__ bb, const float* __restrict__ bih,
                        float* __restrict__ p, float* __restrict__ q) {
    int wave = threadIdx.x >> 6, lane = threadIdx.x & 63;
    int row = blockIdx.x * 4 + wave;
    const float* wr = Wih + (size_t)row * HID;
    float ap = 0.f, aq = 0.f;
    for (int k = lane; k < HID; k += 64) {
        float w = wr[k];
        ap += w * Wb[k];
        aq += w * bb[k];
    }
#pragma unroll
    for (int m = 1; m < 64; m <<= 1) {
        ap += __shfl_xor(ap, m);
        aq += __shfl_xor(aq, m);
    }
    if (lane == 0) {
        p[row] = ap;
        q[row] = aq + bih[row];
    }
}

__global__ __launch_bounds__(NTH, 1) void persist(
    const float* __restrict__ hu, const float* __restrict__ encWhh,
    const float* __restrict__ encBhh, const float* __restrict__ decWih,
    const float* __restrict__ decWhh, const float* __restrict__ decBih,
    const float* __restrict__ decBhh, const float* __restrict__ p,
    const float* __restrict__ q, u64* hbuf, u64* dx0, __half* hstore) {
    const int wg = blockIdx.x, tid = threadIdx.x;
    const int wave = tid >> 6, lane = tid & 63;
    const int j = wg * 8 + wave;
    const int myrep = wg & 7;  // ~XCD by dispatch round-robin; any error only
                               // changes which 32-WG group shares a replica.

    __shared__ float h_lds[HID], x_lds[HID];
    __shared__ float hs_l[8], hy_l[8];
    __shared__ float p_l[24], q_l[24], ebhh[24], dbih[24], dbhh[24];
    __shared__ float u_l[T_ENC];

    // --- LDS preloads (once) ---
    for (int idx = tid; idx < T_ENC; idx += NTH) u_l[idx] = hu[idx];
    if (tid < 24) {
        int g = tid >> 3, jj = tid & 7;
        int r = g * HID + wg * 8 + jj;
        p_l[tid] = p[r];
        q_l[tid] = q[r];
        ebhh[tid] = encBhh[r];
        dbih[tid] = decBih[r];
        dbhh[tid] = decBhh[r];
    }

    // --- encoder Whh rows for unit j -> fp32 registers (3 rows/wave) ---
    float4 We[3][8];
#pragma unroll
    for (int g = 0; g < 3; g++) {
        const float* base = encWhh + (size_t)(g * HID + j) * HID;
#pragma unroll
        for (int i = 0; i < 8; i++)
            We[g][i] = *reinterpret_cast<const float4*>(base + 4 * lane + 256 * i);
    }

    // =========================== encoder: 365 steps =========================
    for (int t = 0; t < T_ENC; t++) {
        if (t == 0) {
            for (int idx = tid; idx < HID; idx += NTH) h_lds[idx] = 0.f;
        } else {
            poll_to_lds(hbuf + (t & 1) * SLOT + myrep * 1024, (unsigned)t, tid,
                        h_lds);
        }
        __syncthreads();

        float4 hreg[8];
#pragma unroll
        for (int i = 0; i < 8; i++)
            hreg[i] = *reinterpret_cast<const float4*>(&h_lds[4 * lane + 256 * i]);

        float v0, v1, v2;
        {
            float a0 = 0.f, a1 = 0.f, a2 = 0.f, a3 = 0.f;
            float b0 = 0.f, b1 = 0.f, b2 = 0.f, b3 = 0.f;
            float c0 = 0.f, c1 = 0.f, c2 = 0.f, c3 = 0.f;
#pragma unroll
            for (int i = 0; i < 8; i++) {
                float4 h4 = hreg[i];
                float4 wr_ = We[0][i], wz_ = We[1][i], wc_ = We[2][i];
                a0 += wr_.x * h4.x; a1 += wr_.y * h4.y;
                a2 += wr_.z * h4.z; a3 += wr_.w * h4.w;
                b0 += wz_.x * h4.x; b1 += wz_.y * h4.y;
                b2 += wz_.z * h4.z; b3 += wz_.w * h4.w;
                c0 += wc_.x * h4.x; c1 += wc_.y * h4.y;
                c2 += wc_.z * h4.z; c3 += wc_.w * h4.w;
            }
            v0 = (a0 + a1) + (a2 + a3);
            v1 = (b0 + b1) + (b2 + b3);
            v2 = (c0 + c1) + (c2 + c3);
        }
#pragma unroll
        for (int m = 1; m < 64; m <<= 1) {
            v0 += __shfl_xor(v0, m);
            v1 += __shfl_xor(v1, m);
            v2 += __shfl_xor(v2, m);
        }

        if (lane == 0) {
            float u = u_l[t];
            float gir = u * p_l[wave] + q_l[wave];
            float giz = u * p_l[8 + wave] + q_l[8 + wave];
            float gic = u * p_l[16 + wave] + q_l[16 + wave];
            float r = sigm(gir + v0 + ebhh[wave]);
            float z = sigm(giz + v1 + ebhh[8 + wave]);
            float c = tanh_f(gic + r * (v2 + ebhh[16 + wave]));
            float hp = (1.f - z) * c + z * h_lds[j];
            hs_l[wave] = sigm(hp);
            hy_l[wave] = hp;
        }
        __syncthreads();
        if (wave == 0 && lane < 32) {
            int i = lane & 3, r = lane >> 2;
            u64 v = mk16((unsigned)(t + 1), hs_l[2 * i], hs_l[2 * i + 1]);
            tst(hbuf + ((t + 1) & 1) * SLOT + r * 1024 + wg * 4 + i, v);
            if (t == T_ENC - 1) {
                u64 y = mk16((unsigned)T_ENC, hy_l[2 * i], hy_l[2 * i + 1]);
                tst(dx0 + r * 1024 + wg * 4 + i, y);
            }
        }
    }

    // --- decoder Wih+Whh rows for unit j -> packed bf16 (6 rows/wave) ---
    unsigned Wd[6][8][2];
#pragma unroll
    for (int g = 0; g < 6; g++) {
        const float* src = (g < 3)
            ? decWih + (size_t)(g * HID + j) * HID
            : decWhh + (size_t)((g - 3) * HID + j) * HID;
#pragma unroll
        for (int i = 0; i < 8; i++) {
            float4 w = *reinterpret_cast<const float4*>(src + 4 * lane + 256 * i);
            Wd[g][i][0] = packbf(w.x, w.y);
            Wd[g][i][1] = packbf(w.z, w.w);
        }
    }

    // =========================== decoder: 90 steps ==========================
    for (int s = 0; s < F_DEC; s++) {
        unsigned rt = (unsigned)(T_ENC + s);
        poll_to_lds(hbuf + (rt & 1) * SLOT + myrep * 1024, rt, tid, h_lds);
        if (s == 0) poll_to_lds(dx0 + myrep * 1024, (unsigned)T_ENC, tid, x_lds);
        __syncthreads();

        const float* xs = (s == 0) ? x_lds : h_lds;
        float4 vx[8], vh[8];
#pragma unroll
        for (int i = 0; i < 8; i++) {
            vx[i] = *reinterpret_cast<const float4*>(&xs[4 * lane + 256 * i]);
            vh[i] = *reinterpret_cast<const float4*>(&h_lds[4 * lane + 256 * i]);
        }

        float d[6];
#pragma unroll
        for (int g = 0; g < 6; g++) {
            float a0 = 0.f, a1 = 0.f, a2 = 0.f, a3 = 0.f;
#pragma unroll
            for (int i = 0; i < 8; i++) {
                unsigned u0 = Wd[g][i][0], u1 = Wd[g][i][1];
                float4 v4 = (g < 3) ? vx[i] : vh[i];
                a0 += __uint_as_float(u0 << 16) * v4.x;
                a1 += __uint_as_float(u0 & 0xffff0000u) * v4.y;
                a2 += __uint_as_float(u1 << 16) * v4.z;
                a3 += __uint_as_float(u1 & 0xffff0000u) * v4.w;
            }
            d[g] = (a0 + a1) + (a2 + a3);
        }
#pragma unroll
        for (int m = 1; m < 64; m <<= 1) {
#pragma unroll
            for (int g = 0; g < 6; g++) d[g] += __shfl_xor(d[g], m);
        }

        if (lane == 0) {
            float r = sigm(d[0] + dbih[wave] + d[3] + dbhh[wave]);
            float z = sigm(d[1] + dbih[8 + wave] + d[4] + dbhh[8 + wave]);
            float c = tanh_f(d[2] + dbih[16 + wave] +
                             r * (d[5] + dbhh[16 + wave]));
            float hp = (1.f - z) * c + z * h_lds[j];
            hy_l[wave] = hp;
            hstore[s * HID + j] = __float2half(hp);  // off-path
        }
        __syncthreads();
        if (wave == 0 && lane < 32) {
            int i = lane & 3, r = lane >> 2;
            u64 v = mk16(rt + 1, hy_l[2 * i], hy_l[2 * i + 1]);
            tst(hbuf + ((rt + 1) & 1) * SLOT + r * 1024 + wg * 4 + i, v);
        }
    }
}

__global__ void sird_k(const float* __restrict__ sird, const float* __restrict__ Wa,
                       const float* __restrict__ ba, const int* __restrict__ ts_p,
                       const __half* __restrict__ hstore, float* __restrict__ out) {
    __shared__ float bpre[96];
    int wave = threadIdx.x >> 6, lane = threadIdx.x & 63;
    const float4* wa4 = (const float4*)Wa;
    for (int s = wave; s < F_DEC; s += 8) {
        const uint4* hr = (const uint4*)(hstore + (size_t)s * HID);
        float acc = 0.f;
#pragma unroll
        for (int m = 0; m < 4; m++) {
            uint4 hh = hr[lane + 64 * m];
            float4 w0 = wa4[2 * (lane + 64 * m)];
            float4 w1 = wa4[2 * (lane + 64 * m) + 1];
            float2 f;
            f = __half22float2(*(__half2*)&hh.x);
            acc += w0.x * f.x + w0.y * f.y;
            f = __half22float2(*(__half2*)&hh.y);
            acc += w0.z * f.x + w0.w * f.y;
            f = __half22float2(*(__half2*)&hh.z);
            acc += w1.x * f.x + w1.y * f.y;
            f = __half22float2(*(__half2*)&hh.w);
            acc += w1.z * f.x + w1.w * f.y;
        }
#pragma unroll
        for (int m = 1; m < 64; m <<= 1) acc += __shfl_xor(acc, m);
        if (lane == 0) bpre[s] = acc;
    }
    __syncthreads();
    if (threadIdx.x == 0) {
        float s = sird[0], i = sird[1], r = sird[2], d = sird[3], n = sird[4];
        float bl = 0.f;
        for (int t = 0; t < F_DEC; t++) {
            float b = 1.f / (1.f + expf(-(bpre[t] + ba[0])));
            bl = b;
            float si = s * i * b / n, ir = i * 0.05f, id = i * 0.01f;
            s -= si;
            i += si - ir - id;
            r += ir;
            d += id;
        }
        int ts = ts_p[0];
        float* foo = out + 5;
        for (int t = 0; t < ts - 1; t++) {
            float si = s * i * bl / n, ir = i * 0.05f, id = i * 0.01f;
            s -= si;
            i += si - ir - id;
            r += ir;
            d += id;
            foo[t * 5 + 0] = s;
            foo[t * 5 + 1] = i;
            foo[t * 5 + 2] = r;
            foo[t * 5 + 3] = d;
            foo[t * 5 + 4] = n;
        }
        out[0] = s;
        out[1] = i;
        out[2] = r;
        out[3] = d;
        out[4] = n;
    }
}

extern "C" void kernel_launch(void* const* d_in, const int* in_sizes, int n_in,
                              void* d_out, int out_size, void* d_ws, size_t ws_size,
                              hipStream_t stream) {
    const float* hu = (const float*)d_in[0];
    const float* sird = (const float*)d_in[1];
    const int* ts = (const int*)d_in[2];
    const float* Wb = (const float*)d_in[3];
    const float* bb = (const float*)d_in[4];
    const float* eWih = (const float*)d_in[5];
    const float* eWhh = (const float*)d_in[6];
    const float* eBih = (const float*)d_in[7];
    const float* eBhh = (const float*)d_in[8];
    const float* dWih = (const float*)d_in[9];
    const float* dWhh = (const float*)d_in[10];
    const float* dBih = (const float*)d_in[11];
    const float* dBhh = (const float*)d_in[12];
    const float* Wa = (const float*)d_in[13];
    const float* ba = (const float*)d_in[14];

    float* wsf = (float*)d_ws;
    float* p = wsf + WS_P;
    float* q = wsf + WS_Q;
    u64* hbuf = (u64*)(wsf + WS_HBUF);
    u64* dx0 = (u64*)(wsf + WS_DX0);
    __half* hstore = (__half*)(wsf + WS_HST);

    hipLaunchKernelGGL(prep_pq, dim3(6144 / 4), dim3(256), 0, stream, eWih, Wb, bb,
                       eBih, p, q);
    hipLaunchKernelGGL(persist, dim3(NWG), dim3(NTH), 0, stream, hu, eWhh, eBhh,
                       dWih, dWhh, dBih, dBhh, p, q, hbuf, dx0, hstore);
    hipLaunchKernelGGL(sird_k, dim3(1), dim3(NTH), 0, stream, sird, Wa, ba, ts,
                       hstore, (float*)d_out);
}